// Round 2
// baseline (715.659 us; speedup 1.0000x reference)
//
#include <hip/hip_runtime.h>

typedef unsigned int u32;
typedef float f32x4 __attribute__((ext_vector_type(4)));

#define N_NODES 30000
#define N_EDGES 600000
#define NBATCH  8
#define KVF     3
#define PER_B   3750          // N_NODES / NBATCH
#define NV      30024         // N_NODES + KVF*NBATCH
#define EV      780000        // N_EDGES + 2*KVF*N_NODES

// output element offsets (float32 elements)
#define O_V      0ULL
#define O_E      2281824ULL
#define O_TROT   168421824ULL
#define O_TTRANS 168692040ULL
#define O_TTSROT 168782112ULL
#define O_TTSTR  175802112ULL
#define O_BATCH  178142112ULL
#define O_EIDX   178172136ULL
#define O_CHAIN  179732136ULL
// total 179762160 f32 elements

// ---- grid layout of the single fused kernel ----
// bid % 4 == 3  -> "other" block (oblk = bid/4, 3125 blocks)
//   oblk <  118 -> node work (30208 threads >= NV)
//   oblk >= 118 -> grid-stride flat fill/eidx work (3007*256 = 769792 threads)
// else          -> edge block, eblk = (bid/4)*3 + (bid%4)  in [0, 9375)
#define TOTAL_BLOCKS 12500
#define NODE_BLOCKS  118
#define FILL_THREADS 769792ULL
// flat fill space in f32x4 units:
#define F_VE   9585000ULL                 // zero virtual E rows  (153.4 MB)
#define F_ROT  (F_VE + 405000ULL)         // eye(3) virtual Tts_rot
#define F_TR   (F_ROT + 135000ULL)        // zero virtual Tts_trans
#define F_END  (F_TR + 390000ULL)         // eidx as f32

// Fast, accurate sincos: keep the f32 angle (same value the reference's
// cos/sin receive), range-reduce it exactly in f64 (cvt+mul+rndne+sub),
// then use HW v_sin/v_cos (operand in revolutions; poly err ~1e-6 on the
// reduced range). Avoids OCML's Payne-Hanek slow path that dominated the
// edge-block critical path for |ang| up to ~3e4 rad.
__device__ __forceinline__ float2 fast_sincos(float ang) {
    double rev = (double)ang * 0.15915494309189535;   // ang / 2pi
    rev -= rint(rev);                                 // v_rndne_f64
    float r = (float)rev;                             // in [-0.5, 0.5] revolutions
    float2 sc;
    sc.x = __builtin_amdgcn_sinf(r);
    sc.y = __builtin_amdgcn_cosf(r);
    return sc;
}

// decouple() of a 3-vector -> 3 direction + 16 rbf features (f32)
__device__ __forceinline__ void decouple_store(float u0, float u1, float u2, float* dst) {
    float sq   = u0 * u0 + u1 * u1 + u2 * u2;
    float norm = sqrtf(sq + 1e-12f);
    float inv  = (norm < 1e-4f) ? 0.f : (1.f / (norm + 1e-6f));
    dst[0] = u0 * inv;
    dst[1] = u1 * inv;
    dst[2] = u2 * inv;
#pragma unroll
    for (int k = 0; k < 16; ++k) {
        float mu = 1.3333333333333333f * (float)k;   // linspace(0,20,16)
        float z  = (norm - mu) * 0.8f;               // sigma = 1.25
        dst[3 + k] = __expf(-z * z);
    }
}

// build local frame from one X row (3 x float4). M is row-major (Rn@Rc);
// the stored rotation R equals M^T. t = CA.
__device__ __forceinline__ void make_frame(float4 x0, float4 x1, float4 x2,
                                           float M[9], float& t0, float& t1, float& t2) {
    float cax = x0.w, cay = x1.x, caz = x1.y;
    float nx = x0.x - cax, ny = x0.y - cay, nz = x0.z - caz;
    float cx = x1.z - cax, cy = x1.w - cay, cz = x2.x - caz;
    float h2   = cx * cx + cy * cy;
    float nrm  = sqrtf(1e-20f + h2);
    float s1 = -cy / nrm, c1 = cx / nrm;
    float nrm2 = sqrtf(1e-20f + h2 + cz * cz);
    float s2 = cz / nrm2, c2 = sqrtf(h2) / nrm2;
    float Rc00 = c2 * c1, Rc01 = -c2 * s1, Rc02 = s2;
    float Rc10 = s1,      Rc11 = c1;
    float Rc20 = -s2 * c1, Rc21 = s2 * s1, Rc22 = c2;
    float nr1 = Rc10 * nx + Rc11 * ny;
    float nr2 = Rc20 * nx + Rc21 * ny + Rc22 * nz;
    float nrm3 = sqrtf(1e-20f + nr1 * nr1 + nr2 * nr2);
    float sn = -nr2 / nrm3, cn = nr1 / nrm3;
    M[0] = Rc00;                   M[1] = Rc01;                   M[2] = Rc02;
    M[3] = cn * Rc10 - sn * Rc20;  M[4] = cn * Rc11 - sn * Rc21;  M[5] = -sn * Rc22;
    M[6] = sn * Rc10 + cn * Rc20;  M[7] = sn * Rc11 + cn * Rc21;  M[8] = cn * Rc22;
    t0 = cax; t1 = cay; t2 = caz;
}

__global__ __launch_bounds__(256) void mega_kernel(
        const float* __restrict__ X, const int* __restrict__ eidx,
        const int* __restrict__ node_idx, const int* __restrict__ batch_id,
        const int* __restrict__ chain, float* __restrict__ out) {
    __shared__ __align__(16) float sE[64 * 213];    // 54528 B
    __shared__ __align__(16) float sRot[64 * 9];    // 2304 B
    __shared__ __align__(16) float sTr[64 * 3];     // 768 B

    int bid = blockIdx.x;
    int tid = threadIdx.x;

    if ((bid & 3) == 3) {
        int oblk = bid >> 2;
        if (oblk < NODE_BLOCKS) {
            // ---------------- node section ----------------
            int i = oblk * 256 + tid;
            if (i >= NV) return;
            if (i < N_NODES) {
                const float4* xv = (const float4*)(X + (size_t)i * 12);
                float4 x0 = xv[0], x1 = xv[1], x2 = xv[2];
                float M[9], cax, cay, caz;
                make_frame(x0, x1, x2, M, cax, cay, caz);
                float* tr = out + O_TROT + (size_t)i * 9;
                tr[0] = M[0]; tr[1] = M[3]; tr[2] = M[6];   // R = M^T row-major
                tr[3] = M[1]; tr[4] = M[4]; tr[5] = M[7];
                tr[6] = M[2]; tr[7] = M[5]; tr[8] = M[8];
                float* tt = out + O_TTRANS + (size_t)i * 3;
                tt[0] = cax; tt[1] = cay; tt[2] = caz;
                // V features: dX_loc[a] = M @ d[a]
                const float* xi = X + (size_t)i * 12;
                float* vp = out + O_V + (size_t)i * 76;
                bool zero_d = (i % PER_B) == 0;
#pragma unroll
                for (int a = 0; a < 4; ++a) {
                    float d0, d1, d2;
                    if (zero_d) {
                        d0 = d1 = d2 = 0.f;
                    } else {
                        const float* pc = xi + a * 3;
                        d0 = pc[0] - pc[-3]; d1 = pc[1] - pc[-2]; d2 = pc[2] - pc[-1];
                    }
                    float u0 = M[0] * d0 + M[1] * d1 + M[2] * d2;
                    float u1 = M[3] * d0 + M[4] * d1 + M[5] * d2;
                    float u2 = M[6] * d0 + M[7] * d1 + M[8] * d2;
                    decouple_store(u0, u1, u2, vp + a * 19);
                }
                out[O_BATCH + i] = (float)batch_id[i];
                out[O_CHAIN + i] = (float)chain[i];
            } else {
                int r = i - N_NODES;
                float kv = (float)(r >> 3);                // repeat(arange(K), B)
                float* vp = out + O_V + (size_t)i * 76;
#pragma unroll
                for (int j = 0; j < 38; ++j) {
                    float freq = __expf((float)(2 * j) * (-9.210340371976184f / 76.f));
                    float2 sc  = fast_sincos(kv * freq);
                    vp[j]      = sc.y;
                    vp[38 + j] = sc.x;
                }
                float* tr = out + O_TROT + (size_t)i * 9;
#pragma unroll
                for (int j = 0; j < 9; ++j) tr[j] = (j == 0 || j == 4 || j == 8) ? 1.f : 0.f;
                float* tt = out + O_TTRANS + (size_t)i * 3;
                tt[0] = 0.f; tt[1] = 0.f; tt[2] = 0.f;
                out[O_BATCH + i] = (float)(r & 7);         // tile(arange(B), K)
                out[O_CHAIN + i] = 1001.f;
            }
            return;
        }
        // ---------------- flat fill / eidx section (grid-stride, f32x4 units) ----------------
        f32x4* oE   = (f32x4*)(out + O_E + 600000ULL * 213ULL);
        f32x4* oRot = (f32x4*)(out + O_TTSROT + 5400000ULL);
        f32x4* oTr  = (f32x4*)(out + O_TTSTR + 1800000ULL);
        f32x4* oEi  = (f32x4*)(out + O_EIDX);
        f32x4 zero; zero.x = zero.y = zero.z = zero.w = 0.f;
        for (size_t f = (size_t)(oblk - NODE_BLOCKS) * 256 + tid; f < F_END; f += FILL_THREADS) {
            if (f < F_VE) {
                __builtin_nontemporal_store(zero, oE + f);
            } else if (f < F_ROT) {
                size_t f2 = f - F_VE;
                u32 a = (u32)((f2 * 4ULL) % 9ULL);
                f32x4 w;
#pragma unroll
                for (int l = 0; l < 4; ++l) {
                    w[l] = (a == 0u || a == 4u || a == 8u) ? 1.f : 0.f;
                    a = (a == 8u) ? 0u : a + 1u;
                }
                __builtin_nontemporal_store(w, oRot + f2);
            } else if (f < F_TR) {
                __builtin_nontemporal_store(zero, oTr + (f - F_ROT));
            } else {
                size_t f4 = f - F_TR;
                int i0 = (int)(f4 * 4);
                f32x4 w;
#pragma unroll
                for (int l = 0; l < 4; ++l) {
                    int i = i0 + l;                   // [0, 2*EV)
                    int row = (i >= EV) ? 1 : 0;
                    int col = i - row * EV;
                    float v;
                    if (col < N_EDGES) {
                        v = (float)eidx[row * N_EDGES + col];
                    } else {
                        int j    = col - N_EDGES;     // [0, 2*K*N)
                        int half = j / 90000;         // K*N = 90000
                        int jj   = j - half * 90000;
                        int k    = jj / N_NODES;
                        int node = jj - k * N_NODES;
                        v = (row == half) ? (float)(N_NODES + batch_id[node] + k * NBATCH)
                                          : (float)node;
                    }
                    w[l] = v;
                }
                __builtin_nontemporal_store(w, oEi + f4);
            }
        }
        return;
    }

    // ---------------- edge section ----------------
    int eblk = (bid >> 2) * 3 + (bid & 3);           // [0, 9375)
    int el   = tid & 63;
    int part = tid >> 6;
    int e = eblk * 64 + el;
    int src = eidx[e];
    int dst = eidx[N_EDGES + e];
    float* se = sE + el * 213;

    if (part <= 1) {
        // diffE: loc[a] = R_src^T (pts[a] - t_src) = M_src @ (pts[a] - t_src)
        // atoms from X[src] (part0) or X[dst] (part1); frame recomputed inline.
        const float4* xs = (const float4*)(X + (size_t)src * 12);
        float4 s0 = xs[0], s1 = xs[1], s2 = xs[2];
        float4 p0 = s0, p1 = s1, p2 = s2;
        if (part == 1) {
            const float4* xd = (const float4*)(X + (size_t)dst * 12);
            p0 = xd[0]; p1 = xd[1]; p2 = xd[2];
        }
        float M[9], ts0, ts1, ts2;
        make_frame(s0, s1, s2, M, ts0, ts1, ts2);
        float px[4] = { p0.x, p0.w, p1.z, p2.y };
        float py[4] = { p0.y, p1.x, p1.w, p2.z };
        float pz[4] = { p0.z, p1.y, p2.x, p2.w };
        float* base = se + (part == 0 ? 0 : 76);
#pragma unroll
        for (int a = 0; a < 4; ++a) {
            float q0 = px[a] - ts0, q1 = py[a] - ts1, q2 = pz[a] - ts2;
            float u0 = M[0] * q0 + M[1] * q1 + M[2] * q2;
            float u1 = M[3] * q0 + M[4] * q1 + M[5] * q2;
            float u2 = M[6] * q0 + M[7] * q1 + M[8] * q2;
            decouple_store(u0, u1, u2, base + a * 19);
        }
    } else if (part == 2) {
        const float4* xs = (const float4*)(X + (size_t)src * 12);
        const float4* xd = (const float4*)(X + (size_t)dst * 12);
        float4 s0 = xs[0], s1 = xs[1], s2 = xs[2];
        float4 d0 = xd[0], d1 = xd[1], d2 = xd[2];
        float Ms[9], ts0, ts1, ts2;
        float Md[9], td0, td1, td2;
        make_frame(s0, s1, s2, Ms, ts0, ts1, ts2);
        make_frame(d0, d1, d2, Md, td0, td1, td2);
        float* sr = sRot + el * 9;
#pragma unroll
        for (int ii = 0; ii < 3; ++ii) {
#pragma unroll
            for (int k = 0; k < 3; ++k) {
                // Rts = Md @ Ms^T   (== R_dst^T @ R_src with R = M^T)
                float q = Md[3 * ii] * Ms[3 * k] + Md[3 * ii + 1] * Ms[3 * k + 1]
                        + Md[3 * ii + 2] * Ms[3 * k + 2];
                sr[ii * 3 + k] = q;            // Tts_rot = Rts row-major
                se[152 + k * 3 + ii] = q;      // E_quant = Rts^T row-major
            }
        }
        float dt0 = ts0 - td0, dt1 = ts1 - td1, dt2 = ts2 - td2;
        float t0 = Md[0] * dt0 + Md[1] * dt1 + Md[2] * dt2;
        float t1 = Md[3] * dt0 + Md[4] * dt1 + Md[5] * dt2;
        float t2 = Md[6] * dt0 + Md[7] * dt1 + Md[8] * dt2;
        float* st = sTr + el * 3;
        st[0] = t0; st[1] = t1; st[2] = t2;
        decouple_store(t0, t1, t2, se + 161);  // E_trans
    } else {
        // pos embedding of (src - dst), 16 features — fast_sincos replaces
        // OCML slow-path trig (|ang| up to ~3e4 rad hit Payne-Hanek).
        float dd = (float)(src - dst);
#pragma unroll
        for (int j = 0; j < 8; ++j) {
            float freq = __expf((float)(2 * j) * (-9.210340371976184f / 16.f));
            float ang  = dd * freq;
            float2 sc  = fast_sincos(ang);
            se[180 + j] = sc.y;
            se[188 + j] = sc.x;
        }
        // E_bias: decouple of scalar b -> 1 + 16 features
        float b    = (float)(node_idx[src] - node_idx[dst]);
        float norm = sqrtf(b * b + 1e-12f);
        se[196] = (norm < 1e-4f) ? 0.f : (b / (norm + 1e-6f));
#pragma unroll
        for (int k = 0; k < 16; ++k) {
            float z = (norm - 1.3333333333333333f * (float)k) * 0.8f;
            se[197 + k] = __expf(-z * z);
        }
    }
    __syncthreads();
    // cooperative contiguous stores: 64*213 f32 = 3408 f32x4; rot 144; trans 48
    const f32x4* s4 = (const f32x4*)sE;
    f32x4* dE = (f32x4*)(out + O_E) + (size_t)eblk * 3408;
    for (int i2 = tid; i2 < 3408; i2 += 256)
        __builtin_nontemporal_store(s4[i2], dE + i2);
    if (tid < 144)
        __builtin_nontemporal_store(((const f32x4*)sRot)[tid],
                                    (f32x4*)(out + O_TTSROT) + (size_t)eblk * 144 + tid);
    if (tid < 48)
        __builtin_nontemporal_store(((const f32x4*)sTr)[tid],
                                    (f32x4*)(out + O_TTSTR) + (size_t)eblk * 48 + tid);
}

extern "C" void kernel_launch(void* const* d_in, const int* in_sizes, int n_in,
                              void* d_out, int out_size, void* d_ws, size_t ws_size,
                              hipStream_t stream) {
    const float* X        = (const float*)d_in[0];
    const int* node_idx   = (const int*)d_in[1];
    const int* eidx       = (const int*)d_in[2];
    const int* batch_id   = (const int*)d_in[3];
    const int* chain      = (const int*)d_in[4];
    float* out = (float*)d_out;
    (void)d_ws; (void)ws_size;

    mega_kernel<<<TOTAL_BLOCKS, 256, 0, stream>>>(X, eidx, node_idx, batch_id, chain, out);
}

// Round 3
// 712.170 us; speedup vs baseline: 1.0049x; 1.0049x over previous
//
#include <hip/hip_runtime.h>

typedef unsigned int u32;
typedef float f32x4 __attribute__((ext_vector_type(4)));

#define N_NODES 30000
#define N_EDGES 600000
#define NBATCH  8
#define KVF     3
#define PER_B   3750          // N_NODES / NBATCH
#define NV      30024         // N_NODES + KVF*NBATCH
#define EV      780000        // N_EDGES + 2*KVF*N_NODES

// output element offsets (float32 elements)
#define O_V      0ULL
#define O_E      2281824ULL
#define O_TROT   168421824ULL
#define O_TTRANS 168692040ULL
#define O_TTSROT 168782112ULL
#define O_TTSTR  175802112ULL
#define O_BATCH  178142112ULL
#define O_EIDX   178172136ULL
#define O_CHAIN  179732136ULL
// total 179762160 f32 elements

// ---- grid layout of the single fused kernel ----
// 32 edges per edge block (LDS 28.8 KB -> 5 blocks/CU vs 2 at 64 edges).
// bid % 7 == 6  -> "other" block (oblk = bid/7, 3125 blocks)
//   oblk <  118 -> node work
//   oblk >= 118 -> grid-stride flat fill/eidx work (3007*256 threads)
// else          -> edge block, eblk = (bid/7)*6 + (bid%7) in [0, 18750)
#define TOTAL_BLOCKS 21875
#define NODE_BLOCKS  118
#define FILL_THREADS 769792ULL
// flat fill space in f32x4 units:
#define F_VE   9585000ULL                 // zero virtual E rows  (153.4 MB)
#define F_ROT  (F_VE + 405000ULL)         // eye(3) virtual Tts_rot
#define F_TR   (F_ROT + 135000ULL)        // zero virtual Tts_trans
#define F_END  (F_TR + 390000ULL)         // eidx as f32

// Fast sincos: exact f64 range reduction (cvt+mul+rndne+sub) + HW v_sin/v_cos
// (operand in revolutions). Avoids OCML Payne-Hanek slow path; err ~1e-6.
__device__ __forceinline__ float2 fast_sincos(float ang) {
    double rev = (double)ang * 0.15915494309189535;   // ang / 2pi
    rev -= rint(rev);
    float r = (float)rev;                             // [-0.5, 0.5] revolutions
    float2 sc;
    sc.x = __builtin_amdgcn_sinf(r);
    sc.y = __builtin_amdgcn_cosf(r);
    return sc;
}

// decouple() of a 3-vector -> 3 direction + 16 rbf features (f32)
__device__ __forceinline__ void decouple_store(float u0, float u1, float u2, float* dst) {
    float sq   = u0 * u0 + u1 * u1 + u2 * u2;
    float norm = sqrtf(sq + 1e-12f);
    float inv  = (norm < 1e-4f) ? 0.f : (1.f / (norm + 1e-6f));
    dst[0] = u0 * inv;
    dst[1] = u1 * inv;
    dst[2] = u2 * inv;
#pragma unroll
    for (int k = 0; k < 16; ++k) {
        float mu = 1.3333333333333333f * (float)k;   // linspace(0,20,16)
        float z  = (norm - mu) * 0.8f;               // sigma = 1.25
        dst[3 + k] = __expf(-z * z);
    }
}

// build local frame from one X row (3 x float4). M is row-major (Rn@Rc);
// the stored rotation R equals M^T. t = CA.
__device__ __forceinline__ void make_frame(float4 x0, float4 x1, float4 x2,
                                           float M[9], float& t0, float& t1, float& t2) {
    float cax = x0.w, cay = x1.x, caz = x1.y;
    float nx = x0.x - cax, ny = x0.y - cay, nz = x0.z - caz;
    float cx = x1.z - cax, cy = x1.w - cay, cz = x2.x - caz;
    float h2   = cx * cx + cy * cy;
    float nrm  = sqrtf(1e-20f + h2);
    float s1 = -cy / nrm, c1 = cx / nrm;
    float nrm2 = sqrtf(1e-20f + h2 + cz * cz);
    float s2 = cz / nrm2, c2 = sqrtf(h2) / nrm2;
    float Rc00 = c2 * c1, Rc01 = -c2 * s1, Rc02 = s2;
    float Rc10 = s1,      Rc11 = c1;
    float Rc20 = -s2 * c1, Rc21 = s2 * s1, Rc22 = c2;
    float nr1 = Rc10 * nx + Rc11 * ny;
    float nr2 = Rc20 * nx + Rc21 * ny + Rc22 * nz;
    float nrm3 = sqrtf(1e-20f + nr1 * nr1 + nr2 * nr2);
    float sn = -nr2 / nrm3, cn = nr1 / nrm3;
    M[0] = Rc00;                   M[1] = Rc01;                   M[2] = Rc02;
    M[3] = cn * Rc10 - sn * Rc20;  M[4] = cn * Rc11 - sn * Rc21;  M[5] = -sn * Rc22;
    M[6] = sn * Rc10 + cn * Rc20;  M[7] = sn * Rc11 + cn * Rc21;  M[8] = cn * Rc22;
    t0 = cax; t1 = cay; t2 = caz;
}

__global__ __launch_bounds__(256) void mega_kernel(
        const float* __restrict__ X, const int* __restrict__ eidx,
        const int* __restrict__ node_idx, const int* __restrict__ batch_id,
        const int* __restrict__ chain, float* __restrict__ out) {
    __shared__ __align__(16) float sE[32 * 213];    // 27264 B
    __shared__ __align__(16) float sRot[32 * 9];    // 1152 B
    __shared__ __align__(16) float sTr[32 * 3];     // 384 B  -> 28.8 KB total

    int bid = blockIdx.x;
    int tid = threadIdx.x;
    int sel = bid % 7;

    if (sel == 6) {
        int oblk = bid / 7;
        if (oblk < NODE_BLOCKS) {
            // ---------------- node section ----------------
            int i = oblk * 256 + tid;
            if (i >= NV) return;
            if (i < N_NODES) {
                const float4* xv = (const float4*)(X + (size_t)i * 12);
                float4 x0 = xv[0], x1 = xv[1], x2 = xv[2];
                float M[9], cax, cay, caz;
                make_frame(x0, x1, x2, M, cax, cay, caz);
                float* tr = out + O_TROT + (size_t)i * 9;
                tr[0] = M[0]; tr[1] = M[3]; tr[2] = M[6];   // R = M^T row-major
                tr[3] = M[1]; tr[4] = M[4]; tr[5] = M[7];
                tr[6] = M[2]; tr[7] = M[5]; tr[8] = M[8];
                float* tt = out + O_TTRANS + (size_t)i * 3;
                tt[0] = cax; tt[1] = cay; tt[2] = caz;
                // V features: dX_loc[a] = M @ d[a]
                const float* xi = X + (size_t)i * 12;
                float* vp = out + O_V + (size_t)i * 76;
                bool zero_d = (i % PER_B) == 0;
#pragma unroll
                for (int a = 0; a < 4; ++a) {
                    float d0, d1, d2;
                    if (zero_d) {
                        d0 = d1 = d2 = 0.f;
                    } else {
                        const float* pc = xi + a * 3;
                        d0 = pc[0] - pc[-3]; d1 = pc[1] - pc[-2]; d2 = pc[2] - pc[-1];
                    }
                    float u0 = M[0] * d0 + M[1] * d1 + M[2] * d2;
                    float u1 = M[3] * d0 + M[4] * d1 + M[5] * d2;
                    float u2 = M[6] * d0 + M[7] * d1 + M[8] * d2;
                    decouple_store(u0, u1, u2, vp + a * 19);
                }
                out[O_BATCH + i] = (float)batch_id[i];
                out[O_CHAIN + i] = (float)chain[i];
            } else {
                int r = i - N_NODES;
                float kv = (float)(r >> 3);                // repeat(arange(K), B)
                float* vp = out + O_V + (size_t)i * 76;
#pragma unroll
                for (int j = 0; j < 38; ++j) {
                    float freq = __expf((float)(2 * j) * (-9.210340371976184f / 76.f));
                    float2 sc  = fast_sincos(kv * freq);
                    vp[j]      = sc.y;
                    vp[38 + j] = sc.x;
                }
                float* tr = out + O_TROT + (size_t)i * 9;
#pragma unroll
                for (int j = 0; j < 9; ++j) tr[j] = (j == 0 || j == 4 || j == 8) ? 1.f : 0.f;
                float* tt = out + O_TTRANS + (size_t)i * 3;
                tt[0] = 0.f; tt[1] = 0.f; tt[2] = 0.f;
                out[O_BATCH + i] = (float)(r & 7);         // tile(arange(B), K)
                out[O_CHAIN + i] = 1001.f;
            }
            return;
        }
        // ---------------- flat fill / eidx section (grid-stride, f32x4 units) ----------------
        f32x4* oE   = (f32x4*)(out + O_E + 600000ULL * 213ULL);
        f32x4* oRot = (f32x4*)(out + O_TTSROT + 5400000ULL);
        f32x4* oTr  = (f32x4*)(out + O_TTSTR + 1800000ULL);
        f32x4* oEi  = (f32x4*)(out + O_EIDX);
        f32x4 zero; zero.x = zero.y = zero.z = zero.w = 0.f;
        for (size_t f = (size_t)(oblk - NODE_BLOCKS) * 256 + tid; f < F_END; f += FILL_THREADS) {
            if (f < F_VE) {
                __builtin_nontemporal_store(zero, oE + f);
            } else if (f < F_ROT) {
                size_t f2 = f - F_VE;
                u32 a = (u32)((f2 * 4ULL) % 9ULL);
                f32x4 w;
#pragma unroll
                for (int l = 0; l < 4; ++l) {
                    w[l] = (a == 0u || a == 4u || a == 8u) ? 1.f : 0.f;
                    a = (a == 8u) ? 0u : a + 1u;
                }
                __builtin_nontemporal_store(w, oRot + f2);
            } else if (f < F_TR) {
                __builtin_nontemporal_store(zero, oTr + (f - F_ROT));
            } else {
                size_t f4 = f - F_TR;
                int i0 = (int)(f4 * 4);
                f32x4 w;
#pragma unroll
                for (int l = 0; l < 4; ++l) {
                    int i = i0 + l;                   // [0, 2*EV)
                    int row = (i >= EV) ? 1 : 0;
                    int col = i - row * EV;
                    float v;
                    if (col < N_EDGES) {
                        v = (float)eidx[row * N_EDGES + col];
                    } else {
                        int j    = col - N_EDGES;     // [0, 2*K*N)
                        int half = j / 90000;         // K*N = 90000
                        int jj   = j - half * 90000;
                        int k    = jj / N_NODES;
                        int node = jj - k * N_NODES;
                        v = (row == half) ? (float)(N_NODES + batch_id[node] + k * NBATCH)
                                          : (float)node;
                    }
                    w[l] = v;
                }
                __builtin_nontemporal_store(w, oEi + f4);
            }
        }
        return;
    }

    // ---------------- edge section: 32 edges, 8 parts of 32 lanes ----------------
    int eblk = (bid / 7) * 6 + sel;                  // [0, 18750)
    int el   = tid & 31;
    int part = tid >> 5;
    int e = eblk * 32 + el;
    int src = eidx[e];
    int dst = eidx[N_EDGES + e];
    float* se = sE + el * 213;

    if (part < 4) {
        // diffE: loc[a] = M_src @ (pts[a] - t_src); pts = concat(X[src], X[dst])
        // part0: src atoms 0,1   part1: src atoms 2,3
        // part2: dst atoms 0,1   part3: dst atoms 2,3
        const float4* xs = (const float4*)(X + (size_t)src * 12);
        float4 s0 = xs[0], s1 = xs[1], s2 = xs[2];
        float4 p0 = s0, p1 = s1, p2 = s2;
        if (part >= 2) {
            const float4* xd = (const float4*)(X + (size_t)dst * 12);
            p0 = xd[0]; p1 = xd[1]; p2 = xd[2];
        }
        float M[9], ts0, ts1, ts2;
        make_frame(s0, s1, s2, M, ts0, ts1, ts2);
        // select the two atoms (compile-safe: explicit branches, register-only)
        float A0x, A0y, A0z, A1x, A1y, A1z;
        if (part & 1) {            // atoms 2,3
            A0x = p1.z; A0y = p1.w; A0z = p2.x;
            A1x = p2.y; A1y = p2.z; A1z = p2.w;
        } else {                   // atoms 0,1
            A0x = p0.x; A0y = p0.y; A0z = p0.z;
            A1x = p0.w; A1y = p1.x; A1z = p1.y;
        }
        float* base = se + (part >= 2 ? 76 : 0) + (part & 1) * 38;
        {
            float q0 = A0x - ts0, q1 = A0y - ts1, q2 = A0z - ts2;
            float u0 = M[0] * q0 + M[1] * q1 + M[2] * q2;
            float u1 = M[3] * q0 + M[4] * q1 + M[5] * q2;
            float u2 = M[6] * q0 + M[7] * q1 + M[8] * q2;
            decouple_store(u0, u1, u2, base);
        }
        {
            float q0 = A1x - ts0, q1 = A1y - ts1, q2 = A1z - ts2;
            float u0 = M[0] * q0 + M[1] * q1 + M[2] * q2;
            float u1 = M[3] * q0 + M[4] * q1 + M[5] * q2;
            float u2 = M[6] * q0 + M[7] * q1 + M[8] * q2;
            decouple_store(u0, u1, u2, base + 19);
        }
    } else if (part == 4) {
        const float4* xs = (const float4*)(X + (size_t)src * 12);
        const float4* xd = (const float4*)(X + (size_t)dst * 12);
        float4 s0 = xs[0], s1 = xs[1], s2 = xs[2];
        float4 d0 = xd[0], d1 = xd[1], d2 = xd[2];
        float Ms[9], ts0, ts1, ts2;
        float Md[9], td0, td1, td2;
        make_frame(s0, s1, s2, Ms, ts0, ts1, ts2);
        make_frame(d0, d1, d2, Md, td0, td1, td2);
        float* sr = sRot + el * 9;
#pragma unroll
        for (int ii = 0; ii < 3; ++ii) {
#pragma unroll
            for (int k = 0; k < 3; ++k) {
                // Rts = Md @ Ms^T   (== R_dst^T @ R_src with R = M^T)
                float q = Md[3 * ii] * Ms[3 * k] + Md[3 * ii + 1] * Ms[3 * k + 1]
                        + Md[3 * ii + 2] * Ms[3 * k + 2];
                sr[ii * 3 + k] = q;            // Tts_rot = Rts row-major
                se[152 + k * 3 + ii] = q;      // E_quant = Rts^T row-major
            }
        }
        float dt0 = ts0 - td0, dt1 = ts1 - td1, dt2 = ts2 - td2;
        float t0 = Md[0] * dt0 + Md[1] * dt1 + Md[2] * dt2;
        float t1 = Md[3] * dt0 + Md[4] * dt1 + Md[5] * dt2;
        float t2 = Md[6] * dt0 + Md[7] * dt1 + Md[8] * dt2;
        float* st = sTr + el * 3;
        st[0] = t0; st[1] = t1; st[2] = t2;
        decouple_store(t0, t1, t2, se + 161);  // E_trans
    } else if (part == 5) {
        // pos embedding of (src - dst), 16 features
        float dd = (float)(src - dst);
#pragma unroll
        for (int j = 0; j < 8; ++j) {
            float freq = __expf((float)(2 * j) * (-9.210340371976184f / 16.f));
            float2 sc  = fast_sincos(dd * freq);
            se[180 + j] = sc.y;
            se[188 + j] = sc.x;
        }
    } else if (part == 6) {
        // E_bias: decouple of scalar b -> 1 + 16 features
        float b    = (float)(node_idx[src] - node_idx[dst]);
        float norm = sqrtf(b * b + 1e-12f);
        se[196] = (norm < 1e-4f) ? 0.f : (b / (norm + 1e-6f));
#pragma unroll
        for (int k = 0; k < 16; ++k) {
            float z = (norm - 1.3333333333333333f * (float)k) * 0.8f;
            se[197 + k] = __expf(-z * z);
        }
    }
    // part 7: no compute, joins the cooperative store
    __syncthreads();
    // cooperative contiguous stores: 32*213 f32 = 1704 f32x4; rot 72; trans 24
    const f32x4* s4 = (const f32x4*)sE;
    f32x4* dE = (f32x4*)(out + O_E) + (size_t)eblk * 1704;
    for (int i2 = tid; i2 < 1704; i2 += 256)
        __builtin_nontemporal_store(s4[i2], dE + i2);
    if (tid < 72)
        __builtin_nontemporal_store(((const f32x4*)sRot)[tid],
                                    (f32x4*)(out + O_TTSROT) + (size_t)eblk * 72 + tid);
    if (tid < 24)
        __builtin_nontemporal_store(((const f32x4*)sTr)[tid],
                                    (f32x4*)(out + O_TTSTR) + (size_t)eblk * 24 + tid);
}

extern "C" void kernel_launch(void* const* d_in, const int* in_sizes, int n_in,
                              void* d_out, int out_size, void* d_ws, size_t ws_size,
                              hipStream_t stream) {
    const float* X        = (const float*)d_in[0];
    const int* node_idx   = (const int*)d_in[1];
    const int* eidx       = (const int*)d_in[2];
    const int* batch_id   = (const int*)d_in[3];
    const int* chain      = (const int*)d_in[4];
    float* out = (float*)d_out;
    (void)d_ws; (void)ws_size;

    mega_kernel<<<TOTAL_BLOCKS, 256, 0, stream>>>(X, eidx, node_idx, batch_id, chain, out);
}